// Round 4
// baseline (168.391 us; speedup 1.0000x reference)
//
#include <hip/hip_runtime.h>
#include <hip/hip_bf16.h>

#define B_ 4
#define T_ 4096
#define C_ 1024
#define H_ 64

typedef __bf16 bf16_t;
typedef __bf16 bf16x8 __attribute__((ext_vector_type(8)));
typedef float f32x4 __attribute__((ext_vector_type(4)));

// ---------------- Kernel A: convert W -> bf16 (Wq pre-scaled by 1/8, exact) --------
__global__ void wcvt_kernel(const float* __restrict__ Wq, const float* __restrict__ Wk,
                            const float* __restrict__ Wv, bf16_t* __restrict__ wbf) {
    int i = blockIdx.x * 256 + threadIdx.x;          // 0 .. 196607
    int m = i >> 16;
    int r = i & 65535;
    const float* src = (m == 0) ? Wq : (m == 1) ? Wk : Wv;
    float s = (m == 0) ? 0.125f : 1.0f;              // fold softmax scale into Wq
    wbf[i] = (bf16_t)(src[r] * s);
}

// ---------------- Kernel B: one-pass QKV projection, reg double-buffered ----------
// grid = 1024 blocks (16 rows each), 256 threads (4 waves). Wave w owns 3 of the 12
// (matrix m, col-tile ct) pairs. Explicit 2-deep pipeline, BK=64: loads for step
// i+1 issue before step i's MFMAs. x read ONCE from HBM.
__global__ __launch_bounds__(256, 3)
void qkv_proj_kernel(const float* __restrict__ x, const bf16_t* __restrict__ wbf,
                     bf16_t* __restrict__ qb, bf16_t* __restrict__ kb,
                     bf16_t* __restrict__ vtb) {
    int tid  = threadIdx.x;
    int w    = tid >> 6;
    int lane = tid & 63;
    int lr   = lane & 15;
    int kg   = lane >> 4;

    int row0 = blockIdx.x * 16;
    const float* xr = x + (size_t)(row0 + lr) * C_ + kg * 8;

    const bf16_t* bp[3];
    int pm[3], pc[3];
    #pragma unroll
    for (int j = 0; j < 3; ++j) {
        int p = w * 3 + j;
        pm[j] = p >> 2;
        pc[j] = p & 3;
        bp[j] = wbf + (size_t)pm[j] * 65536 + (size_t)(pc[j] * 16 + lr) * 1024 + kg * 8;
    }

    f32x4 acc[3];
    #pragma unroll
    for (int j = 0; j < 3; ++j) acc[j] = (f32x4){0.f, 0.f, 0.f, 0.f};

    float4 xb[2][4];
    bf16x8 wb[2][6];

#define LOADX(buf, k0) {                                              \
        xb[buf][0] = *(const float4*)(xr + (k0));                     \
        xb[buf][1] = *(const float4*)(xr + (k0) + 4);                 \
        xb[buf][2] = *(const float4*)(xr + (k0) + 32);                \
        xb[buf][3] = *(const float4*)(xr + (k0) + 36); }
#define LOADW(buf, k0) {                                              \
        _Pragma("unroll")                                             \
        for (int j = 0; j < 3; ++j) {                                 \
            wb[buf][j * 2]     = *(const bf16x8*)(bp[j] + (k0));      \
            wb[buf][j * 2 + 1] = *(const bf16x8*)(bp[j] + (k0) + 32); } }

    LOADX(0, 0);
    LOADW(0, 0);

    #pragma unroll
    for (int it = 0; it < 16; ++it) {
        const int cur = it & 1, nxt = cur ^ 1;
        if (it < 15) {
            LOADX(nxt, (it + 1) * 64);
            LOADW(nxt, (it + 1) * 64);
        }
        #pragma unroll
        for (int s = 0; s < 2; ++s) {
            float4 a0 = xb[cur][s * 2];
            float4 a1 = xb[cur][s * 2 + 1];
            bf16x8 af;
            af[0] = (bf16_t)a0.x; af[1] = (bf16_t)a0.y; af[2] = (bf16_t)a0.z; af[3] = (bf16_t)a0.w;
            af[4] = (bf16_t)a1.x; af[5] = (bf16_t)a1.y; af[6] = (bf16_t)a1.z; af[7] = (bf16_t)a1.w;
            #pragma unroll
            for (int j = 0; j < 3; ++j)
                acc[j] = __builtin_amdgcn_mfma_f32_16x16x32_bf16(af, wb[cur][j * 2 + s], acc[j], 0, 0, 0);
        }
    }
#undef LOADX
#undef LOADW

    #pragma unroll
    for (int j = 0; j < 3; ++j) {
        int m = pm[j];
        int h = pc[j] * 16 + lr;
        #pragma unroll
        for (int i = 0; i < 4; ++i) {
            int t = row0 + kg * 4 + i;
            if (m == 0) {
                qb[(size_t)t * 64 + h] = (bf16_t)acc[j][i];
            } else if (m == 1) {
                kb[(size_t)t * 64 + h] = (bf16_t)acc[j][i];
            } else {
                vtb[((size_t)(t >> 12) * 64 + h) * T_ + (t & 4095)] = (bf16_t)acc[j][i];
            }
        }
    }
}

// ---------------- Kernel C: causal flash attention, KVBLK=128 ----------------
// grid = 1024 blocks (16-row q-tile, diag-heavy first), 256 threads = 4 waves
// splitting the KV range (strided 128-chunks). V loads hidden under softmax;
// defer-rescale; XOR-swizzled per-wave P buffer. LDS combine at block end.
__global__ __launch_bounds__(256, 3)
void attn_kernel(const bf16_t* __restrict__ qb, const bf16_t* __restrict__ kb,
                 const bf16_t* __restrict__ vtb, float* __restrict__ out) {
    __shared__ float  olds[4][16][65];
    __shared__ float  mlds[4][16];
    __shared__ float  llds[4][16];
    __shared__ bf16_t p_raw[4][16 * 128];   // per-wave P, 256B rows, XOR-swizzled

    int tid  = threadIdx.x;
    int w    = tid >> 6;
    int lane = tid & 63;
    int lr   = lane & 15;
    int kg   = lane >> 4;

    int bid  = blockIdx.x;
    int b    = bid & 3;
    int t    = 255 - (bid >> 2);      // long tiles dispatched first
    int qrow0 = t * 16;
    size_t bT = (size_t)b * T_;

    bf16x8 qf[2];
    #pragma unroll
    for (int s = 0; s < 2; ++s)
        qf[s] = *(const bf16x8*)&qb[(bT + qrow0 + lr) * 64 + s * 32 + kg * 8];

    f32x4 o_acc[4];
    float m_i[4], l_i[4];
    #pragma unroll
    for (int ct = 0; ct < 4; ++ct) o_acc[ct] = (f32x4){0.f, 0.f, 0.f, 0.f};
    #pragma unroll
    for (int i = 0; i < 4; ++i) { m_i[i] = -INFINITY; l_i[i] = 0.f; }

    bf16_t* prow = &p_raw[w][0];
    int nchunks = (t >> 3) + 1;       // 128-wide chunks

    for (int c = w; c < nchunks; c += 4) {
        int kv0 = c * 128;

        // ---- K tile loads (16 x 16B, independent; coalesced 64B/row) ----
        const bf16_t* kbase = kb + (bT + kv0 + lr) * 64 + kg * 8;
        bf16x8 kf[16];
        #pragma unroll
        for (int ct = 0; ct < 8; ++ct) {
            kf[ct * 2]     = *(const bf16x8*)(kbase + ct * 16 * 64);
            kf[ct * 2 + 1] = *(const bf16x8*)(kbase + ct * 16 * 64 + 32);
        }

        // ---- S = Q K^T ----
        f32x4 sc[8];
        #pragma unroll
        for (int ct = 0; ct < 8; ++ct) sc[ct] = (f32x4){0.f, 0.f, 0.f, 0.f};
        __builtin_amdgcn_s_setprio(1);
        #pragma unroll
        for (int ct = 0; ct < 8; ++ct)
            #pragma unroll
            for (int s = 0; s < 2; ++s)
                sc[ct] = __builtin_amdgcn_mfma_f32_16x16x32_bf16(qf[s], kf[ct * 2 + s], sc[ct], 0, 0, 0);
        __builtin_amdgcn_s_setprio(0);

        // ---- V tile loads now (independent of softmax; latency hidden) ----
        const bf16_t* vbase = vtb + ((size_t)b * 64 + lr) * T_ + kv0 + kg * 8;
        bf16x8 vf[16];
        #pragma unroll
        for (int ct = 0; ct < 4; ++ct)
            #pragma unroll
            for (int ks = 0; ks < 4; ++ks)
                vf[ct * 4 + ks] = *(const bf16x8*)(vbase + (size_t)ct * 16 * T_ + ks * 32);

        // ---- mask (last chunk only) ----
        if (kv0 + 127 > qrow0) {
            #pragma unroll
            for (int ct = 0; ct < 8; ++ct)
                #pragma unroll
                for (int i = 0; i < 4; ++i) {
                    int col = kv0 + ct * 16 + lr;
                    int rw  = qrow0 + kg * 4 + i;
                    if (col > rw) sc[ct][i] = -INFINITY;
                }
        }

        // ---- online softmax (defer-rescale) ----
        float rmax[4];
        #pragma unroll
        for (int i = 0; i < 4; ++i) {
            float a = fmaxf(fmaxf(sc[0][i], sc[1][i]), fmaxf(sc[2][i], sc[3][i]));
            float bmx = fmaxf(fmaxf(sc[4][i], sc[5][i]), fmaxf(sc[6][i], sc[7][i]));
            rmax[i] = fmaxf(a, bmx);
        }
        #pragma unroll
        for (int off = 1; off < 16; off <<= 1)
            #pragma unroll
            for (int i = 0; i < 4; ++i)
                rmax[i] = fmaxf(rmax[i], __shfl_xor(rmax[i], off));

        bool grow = (rmax[0] > m_i[0]) | (rmax[1] > m_i[1]) |
                    (rmax[2] > m_i[2]) | (rmax[3] > m_i[3]);
        if (__any(grow)) {
            #pragma unroll
            for (int i = 0; i < 4; ++i) {
                float mn = fmaxf(m_i[i], rmax[i]);
                float fs = __expf(m_i[i] - mn);
                m_i[i] = mn;
                l_i[i] *= fs;
                #pragma unroll
                for (int ct = 0; ct < 4; ++ct) o_acc[ct][i] *= fs;
            }
        }

        float rsum[4] = {0.f, 0.f, 0.f, 0.f};
        #pragma unroll
        for (int ct = 0; ct < 8; ++ct)
            #pragma unroll
            for (int i = 0; i < 4; ++i) {
                float p = __expf(sc[ct][i] - m_i[i]);
                int r   = kg * 4 + i;
                int swb = (ct * 32 + lr * 2) ^ (r << 4);   // swizzled byte in row
                prow[r * 128 + (swb >> 1)] = (bf16_t)p;
                rsum[i] += p;
            }
        #pragma unroll
        for (int off = 1; off < 16; off <<= 1)
            #pragma unroll
            for (int i = 0; i < 4; ++i)
                rsum[i] += __shfl_xor(rsum[i], off);
        #pragma unroll
        for (int i = 0; i < 4; ++i) l_i[i] += rsum[i];

        // ---- O += P V ----
        bf16x8 pf[4];
        #pragma unroll
        for (int ks = 0; ks < 4; ++ks) {
            int swb = (ks * 64 + kg * 16) ^ (lr << 4);
            pf[ks] = *(const bf16x8*)&prow[lr * 128 + (swb >> 1)];
        }
        __builtin_amdgcn_s_setprio(1);
        #pragma unroll
        for (int ct = 0; ct < 4; ++ct)
            #pragma unroll
            for (int ks = 0; ks < 4; ++ks)
                o_acc[ct] = __builtin_amdgcn_mfma_f32_16x16x32_bf16(pf[ks], vf[ct * 4 + ks], o_acc[ct], 0, 0, 0);
        __builtin_amdgcn_s_setprio(0);
    }

    // ---- publish per-wave partials (unnormalized O, m, l) ----
    #pragma unroll
    for (int ct = 0; ct < 4; ++ct)
        #pragma unroll
        for (int i = 0; i < 4; ++i)
            olds[w][kg * 4 + i][ct * 16 + lr] = o_acc[ct][i];
    if (lr == 0) {
        #pragma unroll
        for (int i = 0; i < 4; ++i) {
            mlds[w][kg * 4 + i] = m_i[i];
            llds[w][kg * 4 + i] = l_i[i];
        }
    }
    __syncthreads();

    // ---- combine 4 wave-partials -> output ----
    for (int idx = tid; idx < 1024; idx += 256) {
        int r  = idx >> 6;
        int cc = idx & 63;
        float M = fmaxf(fmaxf(mlds[0][r], mlds[1][r]), fmaxf(mlds[2][r], mlds[3][r]));
        float lsum = 0.f, accv = 0.f;
        #pragma unroll
        for (int w4 = 0; w4 < 4; ++w4) {
            float e = __expf(mlds[w4][r] - M);
            lsum += e * llds[w4][r];
            accv += e * olds[w4][r][cc];
        }
        out[(bT + qrow0 + r) * 64 + cc] = accv / lsum;
    }
}

extern "C" void kernel_launch(void* const* d_in, const int* in_sizes, int n_in,
                              void* d_out, int out_size, void* d_ws, size_t ws_size,
                              hipStream_t stream) {
    const float* x  = (const float*)d_in[0];
    const float* Wq = (const float*)d_in[1];
    const float* Wk = (const float*)d_in[2];
    const float* Wv = (const float*)d_in[3];
    float* out = (float*)d_out;

    bf16_t* ws  = (bf16_t*)d_ws;
    bf16_t* wbf = ws;                    // 3*64*1024       = 196608 elems
    bf16_t* qb  = ws + 196608;           // 16384*64        = 1048576
    bf16_t* kb  = qb + 1048576;
    bf16_t* vtb = kb + 1048576;          // [B][64][T]

    wcvt_kernel<<<768, 256, 0, stream>>>(Wq, Wk, Wv, wbf);
    qkv_proj_kernel<<<1024, 256, 0, stream>>>(x, wbf, qb, kb, vtb);
    attn_kernel<<<1024, 256, 0, stream>>>(qb, kb, vtb, out);
}

// Round 5
// 127.018 us; speedup vs baseline: 1.3257x; 1.3257x over previous
//
#include <hip/hip_runtime.h>
#include <hip/hip_bf16.h>

#define B_ 4
#define T_ 4096
#define C_ 1024
#define H_ 64

typedef __bf16 bf16_t;
typedef __bf16 bf16x8 __attribute__((ext_vector_type(8)));
typedef float f32x4 __attribute__((ext_vector_type(4)));

// ---------------- Kernel A: convert W -> bf16 (Wq pre-scaled by 1/8, exact) --------
__global__ void wcvt_kernel(const float* __restrict__ Wq, const float* __restrict__ Wk,
                            const float* __restrict__ Wv, bf16_t* __restrict__ wbf) {
    int i = blockIdx.x * 256 + threadIdx.x;          // 0 .. 196607
    int m = i >> 16;
    int r = i & 65535;
    const float* src = (m == 0) ? Wq : (m == 1) ? Wk : Wv;
    float s = (m == 0) ? 0.125f : 1.0f;              // fold softmax scale into Wq
    wbf[i] = (bf16_t)(src[r] * s);
}

// ---------------- Kernel B: QKV projection, K-split across waves ----------------
// grid = 1024 blocks (16 rows each), 256 threads (4 waves). Wave w owns K slice
// [w*256,(w+1)*256): 4 distinct HBM streams per block, 8-step serial chain per wave,
// then fp32 partial-sum reduce through LDS. x read ONCE from HBM.
__global__ __launch_bounds__(256, 3)
void qkv_proj_kernel(const float* __restrict__ x, const bf16_t* __restrict__ wbf,
                     bf16_t* __restrict__ qb, bf16_t* __restrict__ kb,
                     bf16_t* __restrict__ vtb) {
    __shared__ float olds[4][16][201];   // pitch 201: <=2-way bank conflicts

    int tid  = threadIdx.x;
    int w    = tid >> 6;
    int lane = tid & 63;
    int lr   = lane & 15;
    int kg   = lane >> 4;

    int row0 = blockIdx.x * 16;
    const float*  xr  = x + (size_t)(row0 + lr) * C_ + w * 256 + kg * 8;
    const bf16_t* wb0 = wbf + (size_t)lr * 1024 + w * 256 + kg * 8;

    f32x4 acc[12];
    #pragma unroll
    for (int p = 0; p < 12; ++p) acc[p] = (f32x4){0.f, 0.f, 0.f, 0.f};

    #pragma unroll
    for (int s = 0; s < 8; ++s) {
        float4 a0 = *(const float4*)(xr + s * 32);
        float4 a1 = *(const float4*)(xr + s * 32 + 4);
        bf16x8 af;
        af[0] = (bf16_t)a0.x; af[1] = (bf16_t)a0.y; af[2] = (bf16_t)a0.z; af[3] = (bf16_t)a0.w;
        af[4] = (bf16_t)a1.x; af[5] = (bf16_t)a1.y; af[6] = (bf16_t)a1.z; af[7] = (bf16_t)a1.w;
        #pragma unroll
        for (int p = 0; p < 12; ++p) {
            // pair p: matrix m = p>>2, col-tile ct = p&3
            bf16x8 bf = *(const bf16x8*)(wb0 + (size_t)(p >> 2) * 65536 +
                                         (size_t)(p & 3) * 16384 + s * 32);
            acc[p] = __builtin_amdgcn_mfma_f32_16x16x32_bf16(af, bf, acc[p], 0, 0, 0);
        }
    }

    // publish per-wave partial sums (C/D layout: col=lr, row=kg*4+i)
    #pragma unroll
    for (int p = 0; p < 12; ++p)
        #pragma unroll
        for (int i = 0; i < 4; ++i)
            olds[w][kg * 4 + i][p * 16 + lr] = acc[p][i];
    __syncthreads();

    // reduce 4 K-slices and store (thread = (row r, col tcol), 12 pairs each)
    int r    = tid >> 4;
    int tcol = tid & 15;
    int t    = row0 + r;
    #pragma unroll
    for (int p = 0; p < 12; ++p) {
        float v = olds[0][r][p * 16 + tcol] + olds[1][r][p * 16 + tcol] +
                  olds[2][r][p * 16 + tcol] + olds[3][r][p * 16 + tcol];
        int m = p >> 2;
        int h = (p & 3) * 16 + tcol;
        if (m == 0) {
            qb[(size_t)t * 64 + h] = (bf16_t)v;
        } else if (m == 1) {
            kb[(size_t)t * 64 + h] = (bf16_t)v;
        } else {
            vtb[((size_t)(t >> 12) * 64 + h) * T_ + (t & 4095)] = (bf16_t)v;
        }
    }
}

// ---------------- Kernel C: causal flash attention, 8-way KV split ----------------
// grid = 1024 blocks (16-row q-tile, diag-heavy first), 512 threads = 8 waves
// splitting the KV range (strided 64-chunks, ~4 serial iters/wave). V loads issued
// before softmax; defer-rescale; no main-loop barriers; LDS combine at block end.
__global__ __launch_bounds__(512, 4)
void attn_kernel(const bf16_t* __restrict__ qb, const bf16_t* __restrict__ kb,
                 const bf16_t* __restrict__ vtb, float* __restrict__ out) {
    __shared__ float  olds[8][16][65];
    __shared__ float  mlds[8][16];
    __shared__ float  llds[8][16];
    __shared__ bf16_t p_lds[8][16][68];   // pitch 68: <=2-way conflicts

    int tid  = threadIdx.x;
    int w    = tid >> 6;
    int lane = tid & 63;
    int lr   = lane & 15;
    int kg   = lane >> 4;

    int bid  = blockIdx.x;
    int b    = bid & 3;
    int t    = 255 - (bid >> 2);      // long tiles dispatched first
    int qrow0 = t * 16;
    size_t bT = (size_t)b * T_;

    bf16x8 qf[2];
    #pragma unroll
    for (int s = 0; s < 2; ++s)
        qf[s] = *(const bf16x8*)&qb[(bT + qrow0 + lr) * 64 + s * 32 + kg * 8];

    f32x4 o_acc[4];
    float m_i[4], l_i[4];
    #pragma unroll
    for (int ct = 0; ct < 4; ++ct) o_acc[ct] = (f32x4){0.f, 0.f, 0.f, 0.f};
    #pragma unroll
    for (int i = 0; i < 4; ++i) { m_i[i] = -INFINITY; l_i[i] = 0.f; }

    int nchunks = (t >> 2) + 1;

    for (int c = w; c < nchunks; c += 8) {
        int kv0 = c * 64;

        // ---- K fragment loads (L2-resident) ----
        const bf16_t* kbase = kb + (bT + kv0 + lr) * 64 + kg * 8;
        bf16x8 kf[8];
        #pragma unroll
        for (int ct = 0; ct < 4; ++ct) {
            kf[ct * 2]     = *(const bf16x8*)(kbase + ct * 16 * 64);
            kf[ct * 2 + 1] = *(const bf16x8*)(kbase + ct * 16 * 64 + 32);
        }

        // ---- S = Q K^T ----
        f32x4 sc[4];
        #pragma unroll
        for (int ct = 0; ct < 4; ++ct) sc[ct] = (f32x4){0.f, 0.f, 0.f, 0.f};
        __builtin_amdgcn_s_setprio(1);
        #pragma unroll
        for (int ct = 0; ct < 4; ++ct)
            #pragma unroll
            for (int s = 0; s < 2; ++s)
                sc[ct] = __builtin_amdgcn_mfma_f32_16x16x32_bf16(qf[s], kf[ct * 2 + s], sc[ct], 0, 0, 0);
        __builtin_amdgcn_s_setprio(0);

        // ---- V loads now (independent of softmax; latency hidden under it) ----
        const bf16_t* vbase = vtb + ((size_t)b * 64 + lr) * T_ + kv0 + kg * 8;
        bf16x8 vf[8];
        #pragma unroll
        for (int ct = 0; ct < 4; ++ct)
            #pragma unroll
            for (int s = 0; s < 2; ++s)
                vf[ct * 2 + s] = *(const bf16x8*)(vbase + (size_t)ct * 16 * T_ + s * 32);

        // ---- mask (tail chunk only) ----
        if (kv0 + 63 > qrow0) {
            #pragma unroll
            for (int ct = 0; ct < 4; ++ct)
                #pragma unroll
                for (int i = 0; i < 4; ++i) {
                    int col = kv0 + ct * 16 + lr;
                    int rw  = qrow0 + kg * 4 + i;
                    if (col > rw) sc[ct][i] = -INFINITY;
                }
        }

        // ---- online softmax (defer-rescale) ----
        float rmax[4];
        #pragma unroll
        for (int i = 0; i < 4; ++i)
            rmax[i] = fmaxf(fmaxf(sc[0][i], sc[1][i]), fmaxf(sc[2][i], sc[3][i]));
        #pragma unroll
        for (int off = 1; off < 16; off <<= 1)
            #pragma unroll
            for (int i = 0; i < 4; ++i)
                rmax[i] = fmaxf(rmax[i], __shfl_xor(rmax[i], off));

        bool grow = (rmax[0] > m_i[0]) | (rmax[1] > m_i[1]) |
                    (rmax[2] > m_i[2]) | (rmax[3] > m_i[3]);
        if (__any(grow)) {
            #pragma unroll
            for (int i = 0; i < 4; ++i) {
                float mn = fmaxf(m_i[i], rmax[i]);
                float fs = __expf(m_i[i] - mn);
                m_i[i] = mn;
                l_i[i] *= fs;
                #pragma unroll
                for (int ct = 0; ct < 4; ++ct) o_acc[ct][i] *= fs;
            }
        }

        float rsum[4] = {0.f, 0.f, 0.f, 0.f};
        #pragma unroll
        for (int ct = 0; ct < 4; ++ct)
            #pragma unroll
            for (int i = 0; i < 4; ++i) {
                float p = __expf(sc[ct][i] - m_i[i]);
                p_lds[w][kg * 4 + i][ct * 16 + lr] = (bf16_t)p;
                rsum[i] += p;
            }
        #pragma unroll
        for (int off = 1; off < 16; off <<= 1)
            #pragma unroll
            for (int i = 0; i < 4; ++i)
                rsum[i] += __shfl_xor(rsum[i], off);
        #pragma unroll
        for (int i = 0; i < 4; ++i) l_i[i] += rsum[i];

        // ---- O += P V ----
        bf16x8 pf[2];
        #pragma unroll
        for (int s = 0; s < 2; ++s)
            pf[s] = *(const bf16x8*)&p_lds[w][lr][s * 32 + kg * 8];
        __builtin_amdgcn_s_setprio(1);
        #pragma unroll
        for (int ct = 0; ct < 4; ++ct)
            #pragma unroll
            for (int s = 0; s < 2; ++s)
                o_acc[ct] = __builtin_amdgcn_mfma_f32_16x16x32_bf16(pf[s], vf[ct * 2 + s], o_acc[ct], 0, 0, 0);
        __builtin_amdgcn_s_setprio(0);
    }

    // ---- publish per-wave partials (unnormalized O, m, l) ----
    #pragma unroll
    for (int ct = 0; ct < 4; ++ct)
        #pragma unroll
        for (int i = 0; i < 4; ++i)
            olds[w][kg * 4 + i][ct * 16 + lr] = o_acc[ct][i];
    if (lr == 0) {
        #pragma unroll
        for (int i = 0; i < 4; ++i) {
            mlds[w][kg * 4 + i] = m_i[i];
            llds[w][kg * 4 + i] = l_i[i];
        }
    }
    __syncthreads();

    // ---- combine 8 wave-partials -> output ----
    #pragma unroll
    for (int idx = tid; idx < 1024; idx += 512) {
        int r  = idx >> 6;
        int cc = idx & 63;
        float M = mlds[0][r];
        #pragma unroll
        for (int w8 = 1; w8 < 8; ++w8) M = fmaxf(M, mlds[w8][r]);
        float lsum = 0.f, accv = 0.f;
        #pragma unroll
        for (int w8 = 0; w8 < 8; ++w8) {
            float e = __expf(mlds[w8][r] - M);
            lsum += e * llds[w8][r];
            accv += e * olds[w8][r][cc];
        }
        out[(bT + qrow0 + r) * 64 + cc] = accv / lsum;
    }
}

extern "C" void kernel_launch(void* const* d_in, const int* in_sizes, int n_in,
                              void* d_out, int out_size, void* d_ws, size_t ws_size,
                              hipStream_t stream) {
    const float* x  = (const float*)d_in[0];
    const float* Wq = (const float*)d_in[1];
    const float* Wk = (const float*)d_in[2];
    const float* Wv = (const float*)d_in[3];
    float* out = (float*)d_out;

    bf16_t* ws  = (bf16_t*)d_ws;
    bf16_t* wbf = ws;                    // 3*64*1024       = 196608 elems
    bf16_t* qb  = ws + 196608;           // 16384*64        = 1048576
    bf16_t* kb  = qb + 1048576;
    bf16_t* vtb = kb + 1048576;          // [B][64][T]

    wcvt_kernel<<<768, 256, 0, stream>>>(Wq, Wk, Wv, wbf);
    qkv_proj_kernel<<<1024, 256, 0, stream>>>(x, wbf, qb, kb, vtb);
    attn_kernel<<<1024, 512, 0, stream>>>(qb, kb, vtb, out);
}